// Round 16
// baseline (574.588 us; speedup 1.0000x reference)
//
#include <hip/hip_runtime.h>
#include <hip/hip_bf16.h>
#include <hip/hip_cooperative_groups.h>

#define B_ 4
#define T_ 2048
#define D_ 1024
#define N_ 16
#define TCH 32     // timesteps per chunk
#define NCH 64     // number of chunks (TCH*NCH == T_)

#define GM 8192    // rows of A / C  (B_*T_)
#define GK 1024    // inner dim
#define GN 1024    // cols of C

typedef __attribute__((ext_vector_type(4))) float f32x4;
typedef __attribute__((ext_vector_type(8))) short short8;
typedef unsigned int u32;
typedef unsigned short u16;

#if defined(__has_builtin)
#if __has_builtin(__builtin_amdgcn_exp2f)
#define EXP2(x) __builtin_amdgcn_exp2f(x)
#else
#define EXP2(x) exp2f(x)
#endif
#else
#define EXP2(x) exp2f(x)
#endif

__device__ __forceinline__ float softplus_f(float v) {
    return v > 20.f ? v : log1pf(__expf(v));
}

// f32 -> bf16 round-to-nearest-even
__device__ __forceinline__ u16 f2bf(float f) {
    u32 u = __float_as_uint(f);
    u32 r = (u + 0x7fffu + ((u >> 16) & 1u)) >> 16;
    return (u16)r;
}
// bf16 -> f32
__device__ __forceinline__ float bf2f(u16 v) {
    return __uint_as_float(((u32)v) << 16);
}

// ---------------- single fused f32 -> bf16 convert for x, Wd, Wo ----------------
#define NX4 (GM * GK / 4)          // 2097152 float4s of x
#define NW4 (GK * GN / 4)          // 262144 float4s per weight
__global__ __launch_bounds__(256) void cvt_all(const float* __restrict__ x,
                                               const float* __restrict__ Wd,
                                               const float* __restrict__ Wo,
                                               u16* __restrict__ xbf,
                                               u16* __restrict__ wdbf,
                                               u16* __restrict__ wobf) {
    const int i = blockIdx.x * 256 + threadIdx.x;
    const float* src; u16* dst; int j;
    if (i < NX4)            { src = x;  dst = xbf;  j = i; }
    else if (i < NX4 + NW4) { src = Wd; dst = wdbf; j = i - NX4; }
    else                    { src = Wo; dst = wobf; j = i - NX4 - NW4; }
    float4 v = ((const float4*)src)[j];
    ushort4 o;
    o.x = f2bf(v.x); o.y = f2bf(v.y); o.z = f2bf(v.z); o.w = f2bf(v.w);
    ((ushort4*)dst)[j] = o;
}

// ---------------- bf16 GEMM (R13, unchanged; measured 49 us profiled) ----------
template <int ACT, int OBF>
__global__ __launch_bounds__(512, 8) void gemm_bt(const u16* __restrict__ A,   // [GM,GK] bf16
                                                  const u16* __restrict__ Bw,  // [GN,GK] bf16
                                                  const float* __restrict__ bias, // [GN]
                                                  void* __restrict__ Cout) {
    __shared__ __align__(16) u16 sA[64 * 64];    // 8 KB
    __shared__ __align__(16) u16 sB[128 * 64];   // 16 KB
    const int tid = threadIdx.x;
    const int wid = tid >> 6;      // 0..7
    const int lane = tid & 63;

    const int wg = blockIdx.x;
    const int xcd = wg & 7;
    const int jj = wg >> 3;                   // 0..127
    const int bx = xcd * 16 + (jj & 15);      // m-panel 0..127
    const int by = jj >> 4;                   // n-panel 0..7
    const int m0 = bx * 64;
    const int n0 = by * 128;
    const int wm = wid >> 2;   // 0..1 : 32-row slab
    const int wn = wid & 3;    // 0..3 : 32-col slab

    const int lrow = lane >> 3;
    const int slot = lane & 7;
    const int ksw = (slot ^ lrow) << 3;       // pre-swizzled source k-offset (elems)

    const u16* aP  = A  + (size_t)(m0 + wid * 8 + lrow) * GK + ksw;
    const u16* bP0 = Bw + (size_t)(n0 + wid * 8 + lrow) * GK + ksw;
    const u16* bP1 = Bw + (size_t)(n0 + (wid + 8) * 8 + lrow) * GK + ksw;

    const int wOff = wid * 1024 + lrow * 128 + slot * 16;
    char* const wA  = (char*)sA + wOff;
    char* const wB  = (char*)sB + wOff;       // second B segment at +8192 imm

    const int fr = lane & 15;
    const int g = lane >> 4;
    const int xorv = (fr & 7) << 4;
    const char* const rA0 = (const char*)sA + (wm * 32 + fr) * 128 + ((g * 16) ^ xorv);
    const char* const rA1 = (const char*)sA + (wm * 32 + fr) * 128 + ((64 + g * 16) ^ xorv);
    const char* const rB0 = (const char*)sB + (wn * 32 + fr) * 128 + ((g * 16) ^ xorv);
    const char* const rB1 = (const char*)sB + (wn * 32 + fr) * 128 + ((64 + g * 16) ^ xorv);

    short8 ra, rb0, rb1;       // in-flight staging regs
    f32x4 acc[2][2] = {};

    ra  = *(const short8*)(aP);
    rb0 = *(const short8*)(bP0);
    rb1 = *(const short8*)(bP1);
    *(short8*)(wA)        = ra;
    *(short8*)(wB)        = rb0;
    *(short8*)(wB + 8192) = rb1;
    ra  = *(const short8*)(aP + 64);
    rb0 = *(const short8*)(bP0 + 64);
    rb1 = *(const short8*)(bP1 + 64);
    asm volatile("s_waitcnt lgkmcnt(0)" ::: "memory");
    __builtin_amdgcn_s_barrier();
    asm volatile("" ::: "memory");

    #pragma unroll
    for (int t = 0; t < GK / 64; ++t) {
        #pragma unroll
        for (int kk = 0; kk < 2; ++kk) {
            const char* bA = kk ? rA1 : rA0;
            const char* bB = kk ? rB1 : rB0;
            short8 af[2], bf[2];
            #pragma unroll
            for (int f = 0; f < 2; ++f)
                af[f] = *(const short8*)(bA + f * 2048);
            #pragma unroll
            for (int f = 0; f < 2; ++f)
                bf[f] = *(const short8*)(bB + f * 2048);
            __builtin_amdgcn_s_setprio(1);
            #pragma unroll
            for (int i = 0; i < 2; ++i)
                #pragma unroll
                for (int j2 = 0; j2 < 2; ++j2)
                    acc[i][j2] = __builtin_amdgcn_mfma_f32_16x16x32_bf16(af[i], bf[j2],
                                                                         acc[i][j2], 0, 0, 0);
            __builtin_amdgcn_s_setprio(0);
        }
        if (t + 1 < GK / 64) {
            asm volatile("s_waitcnt lgkmcnt(0)" ::: "memory");   // my ds_reads done
            __builtin_amdgcn_s_barrier();                        // all waves done reading
            asm volatile("" ::: "memory");
            *(short8*)(wA)        = ra;
            *(short8*)(wB)        = rb0;
            *(short8*)(wB + 8192) = rb1;
            asm volatile("s_waitcnt lgkmcnt(0)" ::: "memory");   // my ds_writes done
            __builtin_amdgcn_s_barrier();                        // writes visible
            asm volatile("" ::: "memory");
            if (t + 2 < GK / 64) {
                ra  = *(const short8*)(aP  + (t + 2) * 64);
                rb0 = *(const short8*)(bP0 + (t + 2) * 64);
                rb1 = *(const short8*)(bP1 + (t + 2) * 64);
            }
        }
    }

    // epilogue: C/D layout col=lane&15, row=(lane>>4)*4+reg (m89-verified)
    const int cl = lane & 15;
    const int rg = (lane >> 4) * 4;
    #pragma unroll
    for (int j2 = 0; j2 < 2; ++j2) {
        const int col = n0 + wn * 32 + j2 * 16 + cl;
        const float bv = bias[col];
        #pragma unroll
        for (int i = 0; i < 2; ++i) {
            #pragma unroll
            for (int r = 0; r < 4; ++r) {
                const int rowg = m0 + wm * 32 + i * 16 + rg + r;
                float v = acc[i][j2][r] + bv;
                if (ACT) v = softplus_f(v);
                if (OBF) ((u16*)Cout)[(size_t)rowg * GN + col] = f2bf(v);
                else     ((float*)Cout)[(size_t)rowg * GN + col] = v;
            }
        }
    }
}

// ---------------- standalone scan kernels (R14-proven; fallback path) ----------
__global__ __launch_bounds__(256) void scan_p1(const u16* __restrict__ delta,
                                               const u16* __restrict__ x,
                                               const float* __restrict__ a_log,
                                               float* __restrict__ S,
                                               float* __restrict__ dtsum) {
    const int gid = blockIdx.x * 256 + threadIdx.x;
    const int lane = gid & 63;
    const int w = gid >> 6;
    const int dw = w & 31;
    const int cb = w >> 5;
    const int d = dw * 32 + (lane & 31);
    const int half = lane >> 5;
    const int b = cb & (B_ - 1);
    const int c = cb >> 2;

    float an2[8];
    {
        const float4* a4 = (const float4*)&a_log[d * N_ + half * 8];
        float4 a0 = a4[0], a1 = a4[1];
        an2[0] = (softplus_f(a0.x) + 1e-4f) * 1.44269504f;
        an2[1] = (softplus_f(a0.y) + 1e-4f) * 1.44269504f;
        an2[2] = (softplus_f(a0.z) + 1e-4f) * 1.44269504f;
        an2[3] = (softplus_f(a0.w) + 1e-4f) * 1.44269504f;
        an2[4] = (softplus_f(a1.x) + 1e-4f) * 1.44269504f;
        an2[5] = (softplus_f(a1.y) + 1e-4f) * 1.44269504f;
        an2[6] = (softplus_f(a1.z) + 1e-4f) * 1.44269504f;
        an2[7] = (softplus_f(a1.w) + 1e-4f) * 1.44269504f;
    }

    float s[8];
    #pragma unroll
    for (int n = 0; n < 8; ++n) s[n] = 0.f;
    float dts = 0.f;

    const size_t base = ((size_t)b * T_ + (size_t)c * TCH) * D_ + d;
    float dt = bf2f(delta[base]);
    float xv = bf2f(x[base]);
    for (int i = 0; i < TCH; ++i) {
        float dtn = 0.f, xvn = 0.f;
        if (i + 1 < TCH) {
            dtn = bf2f(delta[base + (size_t)(i + 1) * D_]);
            xvn = bf2f(x[base + (size_t)(i + 1) * D_]);
        }
        const float dtx = dt * xv;
        dts += dt;
        #pragma unroll
        for (int n = 0; n < 8; ++n) {
            const float ab = EXP2(-dt * an2[n]);
            s[n] = fmaf(ab, s[n], dtx);
        }
        dt = dtn; xv = xvn;
    }

    float4* So = (float4*)&S[((size_t)cb * D_ + d) * N_ + half * 8];
    So[0] = make_float4(s[0], s[1], s[2], s[3]);
    So[1] = make_float4(s[4], s[5], s[6], s[7]);
    if (half == 0) dtsum[(size_t)cb * D_ + d] = dts;
}

__global__ __launch_bounds__(256) void scan_p2(const float* __restrict__ S,
                                               const float* __restrict__ dtsum,
                                               const float* __restrict__ a_log,
                                               float* __restrict__ carry_out) {
    const int gid = blockIdx.x * 256 + threadIdx.x;
    const int n = gid & 15;
    const int d = (gid >> 4) & (D_ - 1);
    const int b = gid >> 14;
    const float an2 = (softplus_f(a_log[d * N_ + n]) + 1e-4f) * 1.44269504f;
    float carry = 0.f;
    #pragma unroll 8
    for (int c = 0; c < NCH; ++c) {
        const size_t cb = (size_t)c * B_ + b;
        const size_t idx = (cb * D_ + d) * N_ + n;
        carry_out[idx] = carry;
        const float dts = dtsum[cb * D_ + d];
        const float P = EXP2(-dts * an2);
        carry = fmaf(P, carry, S[idx]);
    }
}

__global__ __launch_bounds__(256) void scan_p3(const u16* __restrict__ delta,
                                               const u16* __restrict__ x,
                                               const float* __restrict__ a_log,
                                               const float* __restrict__ b_param,
                                               const float* __restrict__ carry_in,
                                               u16* __restrict__ y) {
    const int gid = blockIdx.x * 256 + threadIdx.x;
    const int lane = gid & 63;
    const int w = gid >> 6;
    const int dw = w & 31;
    const int cb = w >> 5;
    const int d = dw * 32 + (lane & 31);
    const int half = lane >> 5;
    const int b = cb & (B_ - 1);
    const int c = cb >> 2;

    float an2[8], bp[8];
    {
        const float4* a4 = (const float4*)&a_log[d * N_ + half * 8];
        const float4* b4 = (const float4*)&b_param[d * N_ + half * 8];
        float4 a0 = a4[0], a1 = a4[1];
        float4 v0 = b4[0], v1 = b4[1];
        an2[0] = (softplus_f(a0.x) + 1e-4f) * 1.44269504f;
        an2[1] = (softplus_f(a0.y) + 1e-4f) * 1.44269504f;
        an2[2] = (softplus_f(a0.z) + 1e-4f) * 1.44269504f;
        an2[3] = (softplus_f(a0.w) + 1e-4f) * 1.44269504f;
        an2[4] = (softplus_f(a1.x) + 1e-4f) * 1.44269504f;
        an2[5] = (softplus_f(a1.y) + 1e-4f) * 1.44269504f;
        an2[6] = (softplus_f(a1.z) + 1e-4f) * 1.44269504f;
        an2[7] = (softplus_f(a1.w) + 1e-4f) * 1.44269504f;
        bp[0] = v0.x; bp[1] = v0.y; bp[2] = v0.z; bp[3] = v0.w;
        bp[4] = v1.x; bp[5] = v1.y; bp[6] = v1.z; bp[7] = v1.w;
    }

    float s[8];
    {
        const float4* ci = (const float4*)&carry_in[((size_t)cb * D_ + d) * N_ + half * 8];
        float4 c0 = ci[0], c1 = ci[1];
        s[0] = c0.x; s[1] = c0.y; s[2] = c0.z; s[3] = c0.w;
        s[4] = c1.x; s[5] = c1.y; s[6] = c1.z; s[7] = c1.w;
    }

    const size_t base = ((size_t)b * T_ + (size_t)c * TCH) * D_ + d;
    float dt = bf2f(delta[base]);
    float xv = bf2f(x[base]);
    for (int i = 0; i < TCH; ++i) {
        float dtn = 0.f, xvn = 0.f;
        if (i + 1 < TCH) {
            dtn = bf2f(delta[base + (size_t)(i + 1) * D_]);
            xvn = bf2f(x[base + (size_t)(i + 1) * D_]);
        }
        const float dtx = dt * xv;
        float acc = 0.f;
        #pragma unroll
        for (int n = 0; n < 8; ++n) {
            const float ab = EXP2(-dt * an2[n]);
            s[n] = fmaf(ab, s[n], dtx);
            acc = fmaf(bp[n], s[n], acc);
        }
        const float tot = acc + __shfl_xor(acc, 32);
        if (half == 0) y[base + (size_t)i * D_] = f2bf(tot);
        dt = dtn; xv = xvn;
    }
}

// ---------------- fused scan: 1024 blocks x 2 units/thread, coop grid sync ----
// 1024 blocks x 256 threads = 4 blocks/CU needed (2x margin vs the 8/CU coop
// occupancy ceiling -- R15's 2048-block launch likely hit TooLarge).
// Phase 1 (2 units/thread): local scan -> S, dtsum.  grid.sync
// Phase 2 (blocks 0..255): 64-step carry scan -> carry.  grid.sync
// Phase 3 (2 units/thread): replay -> y (overwrites S region, post-sync safe).
#define CUNITS (NCH * B_ * D_ * 2)     // 1048576 work units
#define CSTRIDE (CUNITS / 2)           // 524288 = units handled per pass
__global__ __launch_bounds__(256, 8) void scan_fused(const u16* __restrict__ delta,
                                                     const u16* __restrict__ x,
                                                     const float* __restrict__ a_log,
                                                     const float* __restrict__ b_param,
                                                     float* __restrict__ S,
                                                     float* __restrict__ dtsum,
                                                     float* __restrict__ carry,
                                                     u16* __restrict__ y) {
    cooperative_groups::grid_group grid = cooperative_groups::this_grid();
    const int tid0 = blockIdx.x * 256 + threadIdx.x;

    // ---------------- phase 1 ----------------
    #pragma unroll
    for (int u = 0; u < 2; ++u) {
        const int gid = tid0 + u * CSTRIDE;
        const int lane = gid & 63;
        const int w = gid >> 6;
        const int dw = w & 31;
        const int cb = w >> 5;
        const int d = dw * 32 + (lane & 31);
        const int half = lane >> 5;
        const int b = cb & (B_ - 1);
        const int c = cb >> 2;

        float an2[8];
        {
            const float4* a4 = (const float4*)&a_log[d * N_ + half * 8];
            float4 a0 = a4[0], a1 = a4[1];
            an2[0] = (softplus_f(a0.x) + 1e-4f) * 1.44269504f;
            an2[1] = (softplus_f(a0.y) + 1e-4f) * 1.44269504f;
            an2[2] = (softplus_f(a0.z) + 1e-4f) * 1.44269504f;
            an2[3] = (softplus_f(a0.w) + 1e-4f) * 1.44269504f;
            an2[4] = (softplus_f(a1.x) + 1e-4f) * 1.44269504f;
            an2[5] = (softplus_f(a1.y) + 1e-4f) * 1.44269504f;
            an2[6] = (softplus_f(a1.z) + 1e-4f) * 1.44269504f;
            an2[7] = (softplus_f(a1.w) + 1e-4f) * 1.44269504f;
        }

        float s[8];
        #pragma unroll
        for (int n = 0; n < 8; ++n) s[n] = 0.f;
        float dts = 0.f;

        const size_t base = ((size_t)b * T_ + (size_t)c * TCH) * D_ + d;
        float dt = bf2f(delta[base]);
        float xv = bf2f(x[base]);
        for (int i = 0; i < TCH; ++i) {
            float dtn = 0.f, xvn = 0.f;
            if (i + 1 < TCH) {
                dtn = bf2f(delta[base + (size_t)(i + 1) * D_]);
                xvn = bf2f(x[base + (size_t)(i + 1) * D_]);
            }
            const float dtx = dt * xv;
            dts += dt;
            #pragma unroll
            for (int n = 0; n < 8; ++n) {
                const float ab = EXP2(-dt * an2[n]);
                s[n] = fmaf(ab, s[n], dtx);
            }
            dt = dtn; xv = xvn;
        }

        float4* So = (float4*)&S[((size_t)cb * D_ + d) * N_ + half * 8];
        So[0] = make_float4(s[0], s[1], s[2], s[3]);
        So[1] = make_float4(s[4], s[5], s[6], s[7]);
        if (half == 0) dtsum[(size_t)cb * D_ + d] = dts;
    }

    __threadfence();
    grid.sync();

    // ---------------- phase 2 (blocks 0..255) ----------------
    if (blockIdx.x < 256) {
        const int g2 = tid0;                 // 0..65535
        const int n2 = g2 & 15;
        const int d2 = (g2 >> 4) & (D_ - 1);
        const int b2 = g2 >> 14;
        const float a2 = (softplus_f(a_log[d2 * N_ + n2]) + 1e-4f) * 1.44269504f;
        float cy = 0.f;
        #pragma unroll 8
        for (int c2 = 0; c2 < NCH; ++c2) {
            const size_t cb2 = (size_t)c2 * B_ + b2;
            const size_t idx = (cb2 * D_ + d2) * N_ + n2;
            carry[idx] = cy;
            const float dts = dtsum[cb2 * D_ + d2];
            const float P = EXP2(-dts * a2);
            cy = fmaf(P, cy, S[idx]);
        }
    }

    __threadfence();
    grid.sync();

    // ---------------- phase 3 ----------------
    #pragma unroll
    for (int u = 0; u < 2; ++u) {
        const int gid = tid0 + u * CSTRIDE;
        const int lane = gid & 63;
        const int w = gid >> 6;
        const int dw = w & 31;
        const int cb = w >> 5;
        const int d = dw * 32 + (lane & 31);
        const int half = lane >> 5;
        const int b = cb & (B_ - 1);
        const int c = cb >> 2;

        float an2[8], bp[8];
        {
            const float4* a4 = (const float4*)&a_log[d * N_ + half * 8];
            const float4* b4 = (const float4*)&b_param[d * N_ + half * 8];
            float4 a0 = a4[0], a1 = a4[1];
            float4 v0 = b4[0], v1 = b4[1];
            an2[0] = (softplus_f(a0.x) + 1e-4f) * 1.44269504f;
            an2[1] = (softplus_f(a0.y) + 1e-4f) * 1.44269504f;
            an2[2] = (softplus_f(a0.z) + 1e-4f) * 1.44269504f;
            an2[3] = (softplus_f(a0.w) + 1e-4f) * 1.44269504f;
            an2[4] = (softplus_f(a1.x) + 1e-4f) * 1.44269504f;
            an2[5] = (softplus_f(a1.y) + 1e-4f) * 1.44269504f;
            an2[6] = (softplus_f(a1.z) + 1e-4f) * 1.44269504f;
            an2[7] = (softplus_f(a1.w) + 1e-4f) * 1.44269504f;
            bp[0] = v0.x; bp[1] = v0.y; bp[2] = v0.z; bp[3] = v0.w;
            bp[4] = v1.x; bp[5] = v1.y; bp[6] = v1.z; bp[7] = v1.w;
        }
        float s[8];
        {
            const float4* ci = (const float4*)&carry[((size_t)cb * D_ + d) * N_ + half * 8];
            float4 c0 = ci[0], c1 = ci[1];
            s[0] = c0.x; s[1] = c0.y; s[2] = c0.z; s[3] = c0.w;
            s[4] = c1.x; s[5] = c1.y; s[6] = c1.z; s[7] = c1.w;
        }

        const size_t base = ((size_t)b * T_ + (size_t)c * TCH) * D_ + d;
        float dt = bf2f(delta[base]);
        float xv = bf2f(x[base]);
        for (int i = 0; i < TCH; ++i) {
            float dtn = 0.f, xvn = 0.f;
            if (i + 1 < TCH) {
                dtn = bf2f(delta[base + (size_t)(i + 1) * D_]);
                xvn = bf2f(x[base + (size_t)(i + 1) * D_]);
            }
            const float dtx = dt * xv;
            float acc = 0.f;
            #pragma unroll
            for (int n = 0; n < 8; ++n) {
                const float ab = EXP2(-dt * an2[n]);
                s[n] = fmaf(ab, s[n], dtx);
                acc = fmaf(bp[n], s[n], acc);
            }
            const float tot = acc + __shfl_xor(acc, 32);
            if (half == 0) y[base + (size_t)i * D_] = f2bf(tot);
            dt = dtn; xv = xvn;
        }
    }
}

// ---------------- launch ----------------
extern "C" void kernel_launch(void* const* d_in, const int* in_sizes, int n_in,
                              void* d_out, int out_size, void* d_ws, size_t ws_size,
                              hipStream_t stream) {
    const float* x      = (const float*)d_in[0];
    const float* Wd     = (const float*)d_in[1];
    const float* bd     = (const float*)d_in[2];
    const float* a_log  = (const float*)d_in[3];
    const float* b_par  = (const float*)d_in[4];
    const float* Wo     = (const float*)d_in[5];
    const float* bo     = (const float*)d_in[6];
    float* out = (float*)d_out;

    char* ws = (char*)d_ws;
    u16*   xbf     = (u16*)(ws);                       //  0..16 MB
    float* S       = (float*)(ws + 16777216);          // 16..32 MB (phases 1/2)
    u16*   ybf     = (u16*)(ws + 16777216);            // 16..32 MB (phase 3 out)
    u16*   deltabf = (u16*)(ws + 33554432);            // 32..48 MB (bf16)
    float* carry   = (float*)(ws + 50331648);          // 48..64 MB
    u16*   wdbf    = (u16*)(ws + 67108864);            // 64 MB +2
    u16*   wobf    = (u16*)(ws + 69206016);            // 66 MB +2
    float* dtsum   = (float*)(ws + 71303168);          // 68 MB +1
    (void)in_sizes; (void)n_in; (void)out_size; (void)ws_size;

    // single fused convert (x, Wd, Wo)
    cvt_all<<<(NX4 + 2 * NW4) / 256, 256, 0, stream>>>(x, Wd, Wo, xbf, wdbf, wobf);

    // delta = softplus(x @ Wd^T + bd), emitted directly as bf16
    gemm_bt<1, 1><<<(GM / 64) * (GN / 128), 512, 0, stream>>>(xbf, wdbf, bd, deltabf);

    // fused blocked scan: cooperative (1024 blocks, 2 units/thread); on any
    // launch failure fall back to the proven 3-kernel path (deterministic).
    {
        void* args[] = { (void*)&deltabf, (void*)&xbf, (void*)&a_log, (void*)&b_par,
                         (void*)&S, (void*)&dtsum, (void*)&carry, (void*)&ybf };
        hipError_t e = hipLaunchCooperativeKernel((void*)scan_fused,
                                                  dim3(CSTRIDE / 256), dim3(256),
                                                  args, 0, stream);
        if (e != hipSuccess) {
            scan_p1<<<CUNITS / 256, 256, 0, stream>>>(deltabf, xbf, a_log, S, dtsum);
            scan_p2<<<B_ * D_ * N_ / 256, 256, 0, stream>>>(S, dtsum, a_log, carry);
            scan_p3<<<CUNITS / 256, 256, 0, stream>>>(deltabf, xbf, a_log, b_par, carry, ybf);
        }
    }

    // out = y @ Wo^T + bo
    gemm_bt<0, 0><<<(GM / 64) * (GN / 128), 512, 0, stream>>>(ybf, wobf, bo, out);
}

// Round 17
// 163.521 us; speedup vs baseline: 3.5139x; 3.5139x over previous
//
#include <hip/hip_runtime.h>
#include <hip/hip_bf16.h>

#define B_ 4
#define T_ 2048
#define D_ 1024
#define N_ 16
#define TCH 32     // timesteps per chunk
#define NCH 64     // number of chunks (TCH*NCH == T_)

#define GM 8192    // rows of A / C  (B_*T_)
#define GK 1024    // inner dim
#define GN 1024    // cols of C

typedef __attribute__((ext_vector_type(4))) float f32x4;
typedef __attribute__((ext_vector_type(8))) short short8;
typedef unsigned int u32;
typedef unsigned short u16;

#if defined(__has_builtin)
#if __has_builtin(__builtin_amdgcn_exp2f)
#define EXP2(x) __builtin_amdgcn_exp2f(x)
#else
#define EXP2(x) exp2f(x)
#endif
#else
#define EXP2(x) exp2f(x)
#endif

__device__ __forceinline__ float softplus_f(float v) {
    return v > 20.f ? v : log1pf(__expf(v));
}

// f32 -> bf16 round-to-nearest-even
__device__ __forceinline__ u16 f2bf(float f) {
    u32 u = __float_as_uint(f);
    u32 r = (u + 0x7fffu + ((u >> 16) & 1u)) >> 16;
    return (u16)r;
}
// bf16 -> f32
__device__ __forceinline__ float bf2f(u16 v) {
    return __uint_as_float(((u32)v) << 16);
}

// ---------------- single fused f32 -> bf16 convert for x, Wd, Wo ----------------
#define NX4 (GM * GK / 4)          // 2097152 float4s of x
#define NW4 (GK * GN / 4)          // 262144 float4s per weight
__global__ __launch_bounds__(256) void cvt_all(const float* __restrict__ x,
                                               const float* __restrict__ Wd,
                                               const float* __restrict__ Wo,
                                               u16* __restrict__ xbf,
                                               u16* __restrict__ wdbf,
                                               u16* __restrict__ wobf) {
    const int i = blockIdx.x * 256 + threadIdx.x;
    const float* src; u16* dst; int j;
    if (i < NX4)            { src = x;  dst = xbf;  j = i; }
    else if (i < NX4 + NW4) { src = Wd; dst = wdbf; j = i - NX4; }
    else                    { src = Wo; dst = wobf; j = i - NX4 - NW4; }
    float4 v = ((const float4*)src)[j];
    ushort4 o;
    o.x = f2bf(v.x); o.y = f2bf(v.y); o.z = f2bf(v.z); o.w = f2bf(v.w);
    ((ushort4*)dst)[j] = o;
}

// ---------------- bf16 GEMM (R13/R14, unchanged; measured 49 us profiled) ------
// 64x128 tile, 8 waves of 32x32, single 24 KB LDS buffer, 2 barriers/K-step,
// reg-staged with t+2 loads issued between barriers, fully-unrolled K-loop,
// hoisted addresses, 1024 blocks -> 4 blocks/CU -> 32 waves/CU, XCD-local
// A-slicing, verified 0-conflict XOR swizzle. OBF: 1 -> bf16 out, 0 -> f32.
template <int ACT, int OBF>
__global__ __launch_bounds__(512, 8) void gemm_bt(const u16* __restrict__ A,   // [GM,GK] bf16
                                                  const u16* __restrict__ Bw,  // [GN,GK] bf16
                                                  const float* __restrict__ bias, // [GN]
                                                  void* __restrict__ Cout) {
    __shared__ __align__(16) u16 sA[64 * 64];    // 8 KB
    __shared__ __align__(16) u16 sB[128 * 64];   // 16 KB
    const int tid = threadIdx.x;
    const int wid = tid >> 6;      // 0..7
    const int lane = tid & 63;

    const int wg = blockIdx.x;
    const int xcd = wg & 7;
    const int jj = wg >> 3;                   // 0..127
    const int bx = xcd * 16 + (jj & 15);      // m-panel 0..127
    const int by = jj >> 4;                   // n-panel 0..7
    const int m0 = bx * 64;
    const int n0 = by * 128;
    const int wm = wid >> 2;   // 0..1 : 32-row slab
    const int wn = wid & 3;    // 0..3 : 32-col slab

    const int lrow = lane >> 3;
    const int slot = lane & 7;
    const int ksw = (slot ^ lrow) << 3;       // pre-swizzled source k-offset (elems)

    const u16* aP  = A  + (size_t)(m0 + wid * 8 + lrow) * GK + ksw;
    const u16* bP0 = Bw + (size_t)(n0 + wid * 8 + lrow) * GK + ksw;
    const u16* bP1 = Bw + (size_t)(n0 + (wid + 8) * 8 + lrow) * GK + ksw;

    const int wOff = wid * 1024 + lrow * 128 + slot * 16;
    char* const wA  = (char*)sA + wOff;
    char* const wB  = (char*)sB + wOff;       // second B segment at +8192 imm

    const int fr = lane & 15;
    const int g = lane >> 4;
    const int xorv = (fr & 7) << 4;
    const char* const rA0 = (const char*)sA + (wm * 32 + fr) * 128 + ((g * 16) ^ xorv);
    const char* const rA1 = (const char*)sA + (wm * 32 + fr) * 128 + ((64 + g * 16) ^ xorv);
    const char* const rB0 = (const char*)sB + (wn * 32 + fr) * 128 + ((g * 16) ^ xorv);
    const char* const rB1 = (const char*)sB + (wn * 32 + fr) * 128 + ((64 + g * 16) ^ xorv);

    short8 ra, rb0, rb1;       // in-flight staging regs
    f32x4 acc[2][2] = {};

    ra  = *(const short8*)(aP);
    rb0 = *(const short8*)(bP0);
    rb1 = *(const short8*)(bP1);
    *(short8*)(wA)        = ra;
    *(short8*)(wB)        = rb0;
    *(short8*)(wB + 8192) = rb1;
    ra  = *(const short8*)(aP + 64);
    rb0 = *(const short8*)(bP0 + 64);
    rb1 = *(const short8*)(bP1 + 64);
    asm volatile("s_waitcnt lgkmcnt(0)" ::: "memory");
    __builtin_amdgcn_s_barrier();
    asm volatile("" ::: "memory");

    #pragma unroll
    for (int t = 0; t < GK / 64; ++t) {
        #pragma unroll
        for (int kk = 0; kk < 2; ++kk) {
            const char* bA = kk ? rA1 : rA0;
            const char* bB = kk ? rB1 : rB0;
            short8 af[2], bf[2];
            #pragma unroll
            for (int f = 0; f < 2; ++f)
                af[f] = *(const short8*)(bA + f * 2048);
            #pragma unroll
            for (int f = 0; f < 2; ++f)
                bf[f] = *(const short8*)(bB + f * 2048);
            __builtin_amdgcn_s_setprio(1);
            #pragma unroll
            for (int i = 0; i < 2; ++i)
                #pragma unroll
                for (int j2 = 0; j2 < 2; ++j2)
                    acc[i][j2] = __builtin_amdgcn_mfma_f32_16x16x32_bf16(af[i], bf[j2],
                                                                         acc[i][j2], 0, 0, 0);
            __builtin_amdgcn_s_setprio(0);
        }
        if (t + 1 < GK / 64) {
            asm volatile("s_waitcnt lgkmcnt(0)" ::: "memory");   // my ds_reads done
            __builtin_amdgcn_s_barrier();                        // all waves done reading
            asm volatile("" ::: "memory");
            *(short8*)(wA)        = ra;
            *(short8*)(wB)        = rb0;
            *(short8*)(wB + 8192) = rb1;
            asm volatile("s_waitcnt lgkmcnt(0)" ::: "memory");   // my ds_writes done
            __builtin_amdgcn_s_barrier();                        // writes visible
            asm volatile("" ::: "memory");
            if (t + 2 < GK / 64) {
                ra  = *(const short8*)(aP  + (t + 2) * 64);
                rb0 = *(const short8*)(bP0 + (t + 2) * 64);
                rb1 = *(const short8*)(bP1 + (t + 2) * 64);
            }
        }
    }

    // epilogue: C/D layout col=lane&15, row=(lane>>4)*4+reg (m89-verified)
    const int cl = lane & 15;
    const int rg = (lane >> 4) * 4;
    #pragma unroll
    for (int j2 = 0; j2 < 2; ++j2) {
        const int col = n0 + wn * 32 + j2 * 16 + cl;
        const float bv = bias[col];
        #pragma unroll
        for (int i = 0; i < 2; ++i) {
            #pragma unroll
            for (int r = 0; r < 4; ++r) {
                const int rowg = m0 + wm * 32 + i * 16 + rg + r;
                float v = acc[i][j2][r] + bv;
                if (ACT) v = softplus_f(v);
                if (OBF) ((u16*)Cout)[(size_t)rowg * GN + col] = f2bf(v);
                else     ((float*)Cout)[(size_t)rowg * GN + col] = v;
            }
        }
    }
}

// ---------------- scan phase 1: per-chunk local scan, n-split x2, prefetched ----
// S stored as bf16 (halves S traffic; error attenuated by b_param scale 0.02)
__global__ __launch_bounds__(256) void scan_p1(const u16* __restrict__ delta,  // bf16
                                               const u16* __restrict__ x,      // bf16
                                               const float* __restrict__ a_log,
                                               u16* __restrict__ S,         // [NCH,B,D,N] bf16
                                               float* __restrict__ dtsum) { // [NCH,B,D]
    const int gid = blockIdx.x * 256 + threadIdx.x;
    const int lane = gid & 63;
    const int w = gid >> 6;
    const int dw = w & 31;         // 32 waves per (c,b)
    const int cb = w >> 5;         // 0..255 = c*B+b
    const int d = dw * 32 + (lane & 31);
    const int half = lane >> 5;
    const int b = cb & (B_ - 1);
    const int c = cb >> 2;

    float an2[8];
    {
        const float4* a4 = (const float4*)&a_log[d * N_ + half * 8];
        float4 a0 = a4[0], a1 = a4[1];
        an2[0] = (softplus_f(a0.x) + 1e-4f) * 1.44269504f;
        an2[1] = (softplus_f(a0.y) + 1e-4f) * 1.44269504f;
        an2[2] = (softplus_f(a0.z) + 1e-4f) * 1.44269504f;
        an2[3] = (softplus_f(a0.w) + 1e-4f) * 1.44269504f;
        an2[4] = (softplus_f(a1.x) + 1e-4f) * 1.44269504f;
        an2[5] = (softplus_f(a1.y) + 1e-4f) * 1.44269504f;
        an2[6] = (softplus_f(a1.z) + 1e-4f) * 1.44269504f;
        an2[7] = (softplus_f(a1.w) + 1e-4f) * 1.44269504f;
    }

    float s[8];
    #pragma unroll
    for (int n = 0; n < 8; ++n) s[n] = 0.f;
    float dts = 0.f;

    const size_t base = ((size_t)b * T_ + (size_t)c * TCH) * D_ + d;
    float dt = bf2f(delta[base]);
    float xv = bf2f(x[base]);
    for (int i = 0; i < TCH; ++i) {
        float dtn = 0.f, xvn = 0.f;
        if (i + 1 < TCH) {
            dtn = bf2f(delta[base + (size_t)(i + 1) * D_]);
            xvn = bf2f(x[base + (size_t)(i + 1) * D_]);
        }
        const float dtx = dt * xv;
        dts += dt;
        #pragma unroll
        for (int n = 0; n < 8; ++n) {
            const float ab = EXP2(-dt * an2[n]);
            s[n] = fmaf(ab, s[n], dtx);
        }
        dt = dtn; xv = xvn;
    }

    short8 sv;
    #pragma unroll
    for (int n = 0; n < 8; ++n) sv[n] = (short)f2bf(s[n]);
    *(short8*)&S[((size_t)cb * D_ + d) * N_ + half * 8] = sv;
    if (half == 0) dtsum[(size_t)cb * D_ + d] = dts;
}

// ---------------- scan phase 2: 64-step carry scan across chunks (bf16 S/carry) -
__global__ __launch_bounds__(256) void scan_p2(const u16* __restrict__ S,
                                               const float* __restrict__ dtsum,
                                               const float* __restrict__ a_log,
                                               u16* __restrict__ carry_out) {
    const int gid = blockIdx.x * 256 + threadIdx.x;
    const int n = gid & 15;
    const int d = (gid >> 4) & (D_ - 1);
    const int b = gid >> 14;
    const float an2 = (softplus_f(a_log[d * N_ + n]) + 1e-4f) * 1.44269504f;
    float carry = 0.f;
    #pragma unroll 8
    for (int c = 0; c < NCH; ++c) {
        const size_t cb = (size_t)c * B_ + b;
        const size_t idx = (cb * D_ + d) * N_ + n;
        carry_out[idx] = f2bf(carry);                 // carry INTO chunk c
        const float dts = dtsum[cb * D_ + d];
        const float P = EXP2(-dts * an2);             // prod of a_bar over chunk
        carry = fmaf(P, carry, bf2f(S[idx]));
    }
}

// ---------------- scan phase 3: replay with true carry, n-split x2, prefetched --
__global__ __launch_bounds__(256) void scan_p3(const u16* __restrict__ delta,   // bf16
                                               const u16* __restrict__ x,       // bf16
                                               const float* __restrict__ a_log,
                                               const float* __restrict__ b_param,
                                               const u16* __restrict__ carry_in, // bf16
                                               u16* __restrict__ y) {  // [B,T,D] bf16
    const int gid = blockIdx.x * 256 + threadIdx.x;
    const int lane = gid & 63;
    const int w = gid >> 6;
    const int dw = w & 31;
    const int cb = w >> 5;
    const int d = dw * 32 + (lane & 31);
    const int half = lane >> 5;
    const int b = cb & (B_ - 1);
    const int c = cb >> 2;

    float an2[8], bp[8];
    {
        const float4* a4 = (const float4*)&a_log[d * N_ + half * 8];
        const float4* b4 = (const float4*)&b_param[d * N_ + half * 8];
        float4 a0 = a4[0], a1 = a4[1];
        float4 v0 = b4[0], v1 = b4[1];
        an2[0] = (softplus_f(a0.x) + 1e-4f) * 1.44269504f;
        an2[1] = (softplus_f(a0.y) + 1e-4f) * 1.44269504f;
        an2[2] = (softplus_f(a0.z) + 1e-4f) * 1.44269504f;
        an2[3] = (softplus_f(a0.w) + 1e-4f) * 1.44269504f;
        an2[4] = (softplus_f(a1.x) + 1e-4f) * 1.44269504f;
        an2[5] = (softplus_f(a1.y) + 1e-4f) * 1.44269504f;
        an2[6] = (softplus_f(a1.z) + 1e-4f) * 1.44269504f;
        an2[7] = (softplus_f(a1.w) + 1e-4f) * 1.44269504f;
        bp[0] = v0.x; bp[1] = v0.y; bp[2] = v0.z; bp[3] = v0.w;
        bp[4] = v1.x; bp[5] = v1.y; bp[6] = v1.z; bp[7] = v1.w;
    }

    float s[8];
    {
        short8 cv = *(const short8*)&carry_in[((size_t)cb * D_ + d) * N_ + half * 8];
        #pragma unroll
        for (int n = 0; n < 8; ++n) s[n] = bf2f((u16)cv[n]);
    }

    const size_t base = ((size_t)b * T_ + (size_t)c * TCH) * D_ + d;
    float dt = bf2f(delta[base]);
    float xv = bf2f(x[base]);
    for (int i = 0; i < TCH; ++i) {
        float dtn = 0.f, xvn = 0.f;
        if (i + 1 < TCH) {
            dtn = bf2f(delta[base + (size_t)(i + 1) * D_]);
            xvn = bf2f(x[base + (size_t)(i + 1) * D_]);
        }
        const float dtx = dt * xv;
        float acc = 0.f;
        #pragma unroll
        for (int n = 0; n < 8; ++n) {
            const float ab = EXP2(-dt * an2[n]);
            s[n] = fmaf(ab, s[n], dtx);
            acc = fmaf(bp[n], s[n], acc);
        }
        const float tot = acc + __shfl_xor(acc, 32);
        if (half == 0) y[base + (size_t)i * D_] = f2bf(tot);
        dt = dtn; xv = xvn;
    }
}

// ---------------- launch ----------------
extern "C" void kernel_launch(void* const* d_in, const int* in_sizes, int n_in,
                              void* d_out, int out_size, void* d_ws, size_t ws_size,
                              hipStream_t stream) {
    const float* x      = (const float*)d_in[0];
    const float* Wd     = (const float*)d_in[1];
    const float* bd     = (const float*)d_in[2];
    const float* a_log  = (const float*)d_in[3];
    const float* b_par  = (const float*)d_in[4];
    const float* Wo     = (const float*)d_in[5];
    const float* bo     = (const float*)d_in[6];
    float* out = (float*)d_out;

    char* ws = (char*)d_ws;
    // xbf stays live the whole run (GEMM1 A + scan input)
    u16*   xbf     = (u16*)(ws);                       //  0..16 MB
    u16*   S16     = (u16*)(ws + 16777216);            // 16..24.4 MB (bf16, p1/p2)
    u16*   ybf     = (u16*)(ws + 16777216);            // 16..32 MB (p3 out; S dead)
    u16*   deltabf = (u16*)(ws + 33554432);            // 32..48 MB (bf16)
    u16*   carry16 = (u16*)(ws + 50331648);            // 48..56.4 MB (bf16)
    u16*   wdbf    = (u16*)(ws + 67108864);            // 64 MB +2
    u16*   wobf    = (u16*)(ws + 69206016);            // 66 MB +2
    float* dtsum   = (float*)(ws + 71303168);          // 68 MB +1
    (void)in_sizes; (void)n_in; (void)out_size; (void)ws_size;

    // single fused convert (x, Wd, Wo)
    cvt_all<<<(NX4 + 2 * NW4) / 256, 256, 0, stream>>>(x, Wd, Wo, xbf, wdbf, wobf);

    // delta = softplus(x @ Wd^T + bd), emitted directly as bf16
    gemm_bt<1, 1><<<(GM / 64) * (GN / 128), 512, 0, stream>>>(xbf, wdbf, bd, deltabf);

    // blocked scan (p1/p3: n-split x2 -> 2048 blocks; bf16 everywhere)
    scan_p1<<<NCH * B_ * D_ * 2 / 256, 256, 0, stream>>>(deltabf, xbf, a_log, S16, dtsum);
    scan_p2<<<B_ * D_ * N_ / 256, 256, 0, stream>>>(S16, dtsum, a_log, carry16);
    scan_p3<<<NCH * B_ * D_ * 2 / 256, 256, 0, stream>>>(deltabf, xbf, a_log, b_par, carry16, ybf);

    // out = y @ Wo^T + bo
    gemm_bt<0, 0><<<(GM / 64) * (GN / 128), 512, 0, stream>>>(ybf, wobf, bo, out);
}